// Round 9
// baseline (241.645 us; speedup 1.0000x reference)
//
#include <hip/hip_runtime.h>

#define T_SEQ 512
#define BATCH 4096
#define D_IN  5
#define H     15
#define G4    60   // 4*H
#define OUTN  25
#define NITER (T_SEQ + 4)

#define M_SIG  (-1.4426950408889634f)   // sigmoid exp2 prescale
#define M_TANH (-2.8853901f)            // tanh exp2 prescale (-2*log2e)

// ---------- helpers ----------
__device__ __forceinline__ float fast_exp2(float x) {
#if __has_builtin(__builtin_amdgcn_exp2f)
  return __builtin_amdgcn_exp2f(x);
#else
  return exp2f(x);
#endif
}

__device__ __forceinline__ float fast_rcp(float x) {
#if __has_builtin(__builtin_amdgcn_rcpf)
  return __builtin_amdgcn_rcpf(x);
#else
  return 1.0f / x;
#endif
}

__device__ __forceinline__ float rl(float v, int lane) {
  return __int_as_float(__builtin_amdgcn_readlane(__float_as_int(v), lane));
}

// broadcast quad-lane K (0..3) to all 4 lanes of each quad via DPP quad_perm
template <int K>
__device__ __forceinline__ float qbcast(float v) {
  return __int_as_float(__builtin_amdgcn_update_dpp(
      0, __float_as_int(v), K * 0x55, 0xF, 0xF, true));
}

// Workgroup barrier WITHOUT vmcnt(0) drain: order LDS (lgkmcnt) only, so
// global loads (xw prefetch) and stores (out) stay in flight across it.
__device__ __forceinline__ void wg_barrier() {
  asm volatile("s_waitcnt lgkmcnt(0)" ::: "memory");
  __builtin_amdgcn_s_barrier();
  asm volatile("" ::: "memory");
}

// ---------- kernel A ----------
// xw0[t][g] = (x[t,B-1,:]·w_ih0[g,:] + b_ih0[g] + b_hh0[g]) * m(g)
__global__ void precompute_xw0(const float* __restrict__ x,
                               const float* __restrict__ w_ih0,
                               const float* __restrict__ b_ih0,
                               const float* __restrict__ b_hh0,
                               float* __restrict__ xw0) {
  int idx = blockIdx.x * blockDim.x + threadIdx.x;
  if (idx >= T_SEQ * G4) return;
  int t = idx / G4;
  int g = idx - t * G4;
  const float* xp = x + ((size_t)t * BATCH + (BATCH - 1)) * D_IN;
  float a = b_ih0[g] + b_hh0[g];
#pragma unroll
  for (int d = 0; d < D_IN; ++d) a = fmaf(xp[d], w_ih0[g * D_IN + d], a);
  float m = (g / H == 2) ? M_TANH : M_SIG;
  xw0[idx] = a * m;
}

// ---------- kernel B: wave-specialized pipeline, 3 waves ----------
// W0: layer-0 step t0=i      -> writes h0 to LDS ring
// W1: layer-1 step t1=i-2    -> reads h0 (prefetched), writes h1 to LDS ring
// W2: linear  step t2=i-4    -> reads h1 (prefetched), stores out
// One raw barrier per iteration; LDS ring depth 4 (>= skew 2 + 2 margin).
__global__ void __launch_bounds__(192, 1)
lstm_pipe(const float* __restrict__ xw0,
          const float* __restrict__ w_hh0,
          const float* __restrict__ w_ih1,
          const float* __restrict__ w_hh1,
          const float* __restrict__ b_ih1,
          const float* __restrict__ b_hh1,
          const float* __restrict__ w_lin,
          const float* __restrict__ b_lin,
          float* __restrict__ out) {
  __shared__ __align__(16) float h0buf[4][16];
  __shared__ __align__(16) float h1buf[4][16];

  const int tid  = threadIdx.x;
  const int wid  = tid >> 6;
  const int lane = tid & 63;
  const int ty = lane & 3;
  const int j  = lane >> 2;                  // unit 0..15 (15 = idle quad)
  const int g  = (j < H) ? (ty * H + j) : 0; // PyTorch gate row (i,f,g,o)

  const bool  isT  = (ty == 2);
  const float m    = isT ? M_TANH : M_SIG;
  const float scv  = isT ? (2.0f * M_TANH) : 1.0f;
  const float offv = isT ? (-M_TANH) : 0.0f;

  if (wid == 0) {
    // ---------------- W0: layer 0 ----------------
    float w0[H];
#pragma unroll
    for (int k = 0; k < H; ++k) w0[k] = w_hh0[g * H + k] * m;
    float sh0[H];
#pragma unroll
    for (int k = 0; k < H; ++k) sh0[k] = 0.0f;
    float c0 = 0.0f;
    float xw_cur = xw0[g];
    float xw_n1  = xw0[G4 + g];

    for (int i = 0; i < NITER; ++i) {
      if (i < T_SEQ) {
        int tn = (i + 2 < T_SEQ) ? (i + 2) : 0;
        float xw_n2 = xw0[tn * G4 + g];

        float a0 = xw_cur, a1 = 0.0f, a2 = 0.0f;
#pragma unroll
        for (int k = 0; k < 5; ++k)   a0 = fmaf(w0[k], sh0[k], a0);
#pragma unroll
        for (int k = 5; k < 10; ++k)  a1 = fmaf(w0[k], sh0[k], a1);
#pragma unroll
        for (int k = 10; k < 15; ++k) a2 = fmaf(w0[k], sh0[k], a2);
        float a = a0 + (a1 + a2);
        float e = fast_exp2(a);
        float s = fast_rcp(1.0f + e);
        float v = fmaf(s, scv, offv);
        float vi = qbcast<0>(v), vf = qbcast<1>(v), vg = qbcast<2>(v), vo = qbcast<3>(v);
        c0 = fmaf(vf, c0, vi * vg);
        float th = fmaf(fast_rcp(1.0f + fast_exp2(c0)), 2.0f, -1.0f);
        float h0v = vo * th;

        if (ty == 0 && j < H) h0buf[i & 3][j] = h0v;
#pragma unroll
        for (int k = 0; k < H; ++k) sh0[k] = rl(h0v, 4 * k);

        xw_cur = xw_n1;
        xw_n1  = xw_n2;
      }
      wg_barrier();
    }
  } else if (wid == 1) {
    // ---------------- W1: layer 1 ----------------
    float wi1[H], wh1[H];
#pragma unroll
    for (int k = 0; k < H; ++k) {
      wi1[k] = w_ih1[g * H + k] * m;
      wh1[k] = w_hh1[g * H + k] * m;
    }
    const float bias1 = (b_ih1[g] + b_hh1[g]) * m;
    float sh1[H];
#pragma unroll
    for (int k = 0; k < H; ++k) sh1[k] = 0.0f;
    float c1 = 0.0f;
    float4 hA = {0,0,0,0}, hB = {0,0,0,0}, hC = {0,0,0,0}, hD = {0,0,0,0};
    float4 nA = {0,0,0,0}, nB = {0,0,0,0}, nC = {0,0,0,0}, nD = {0,0,0,0};

    for (int i = 0; i < NITER; ++i) {
      int t1 = i - 2;
      if (0 <= t1 && t1 < T_SEQ) {
        // u = bias1 + wi1·h0[t1] (hA..hD) + wh1·sh1  (same association as before)
        float u0 = bias1, u1 = 0.0f, u2 = 0.0f, u3 = 0.0f, u4 = 0.0f, u5 = 0.0f;
        u0 = fmaf(wi1[0],  hA.x, u0); u0 = fmaf(wi1[1],  hA.y, u0);
        u0 = fmaf(wi1[2],  hA.z, u0); u0 = fmaf(wi1[3],  hA.w, u0);
        u0 = fmaf(wi1[4],  hB.x, u0);
        u1 = fmaf(wi1[5],  hB.y, u1); u1 = fmaf(wi1[6],  hB.z, u1);
        u1 = fmaf(wi1[7],  hB.w, u1); u1 = fmaf(wi1[8],  hC.x, u1);
        u1 = fmaf(wi1[9],  hC.y, u1);
        u2 = fmaf(wi1[10], hC.z, u2); u2 = fmaf(wi1[11], hC.w, u2);
        u2 = fmaf(wi1[12], hD.x, u2); u2 = fmaf(wi1[13], hD.y, u2);
        u2 = fmaf(wi1[14], hD.z, u2);
#pragma unroll
        for (int k = 0; k < 5; ++k)   u3 = fmaf(wh1[k], sh1[k], u3);
#pragma unroll
        for (int k = 5; k < 10; ++k)  u4 = fmaf(wh1[k], sh1[k], u4);
#pragma unroll
        for (int k = 10; k < 15; ++k) u5 = fmaf(wh1[k], sh1[k], u5);
        float b = ((u0 + u1) + (u2 + u3)) + (u4 + u5);

        float e = fast_exp2(b);
        float s = fast_rcp(1.0f + e);
        float v = fmaf(s, scv, offv);
        float qi = qbcast<0>(v), qf = qbcast<1>(v), qg = qbcast<2>(v), qo = qbcast<3>(v);
        c1 = fmaf(qf, c1, qi * qg);
        float th = fmaf(fast_rcp(1.0f + fast_exp2(c1)), 2.0f, -1.0f);
        float h1v = qo * th;

        if (ty == 0 && j < H) h1buf[t1 & 3][j] = h1v;
#pragma unroll
        for (int k = 0; k < H; ++k) sh1[k] = rl(h1v, 4 * k);
      }
      // prefetch h0[i-1] (for t1 = i-1 computed next iteration)
      if (i - 1 >= 0 && i - 1 < T_SEQ) {
        const float4* p = (const float4*)(&h0buf[(i - 1) & 3][0]);
        nA = p[0]; nB = p[1]; nC = p[2]; nD = p[3];
      }
      wg_barrier();
      hA = nA; hB = nB; hC = nC; hD = nD;
    }
  } else {
    // ---------------- W2: linear ----------------
    const int o = (lane < OUTN) ? lane : 0;
    float wl[H];
#pragma unroll
    for (int k = 0; k < H; ++k) wl[k] = w_lin[o * H + k];
    const float bl = b_lin[o];
    float4 hA = {0,0,0,0}, hB = {0,0,0,0}, hC = {0,0,0,0}, hD = {0,0,0,0};
    float4 nA = {0,0,0,0}, nB = {0,0,0,0}, nC = {0,0,0,0}, nD = {0,0,0,0};

    for (int i = 0; i < NITER; ++i) {
      int t2 = i - 4;
      if (0 <= t2) {  // t2 < T_SEQ guaranteed by NITER
        float o0 = bl, o1 = 0.0f, o2 = 0.0f;
        o0 = fmaf(wl[0],  hA.x, o0); o0 = fmaf(wl[1],  hA.y, o0);
        o0 = fmaf(wl[2],  hA.z, o0); o0 = fmaf(wl[3],  hA.w, o0);
        o0 = fmaf(wl[4],  hB.x, o0);
        o1 = fmaf(wl[5],  hB.y, o1); o1 = fmaf(wl[6],  hB.z, o1);
        o1 = fmaf(wl[7],  hB.w, o1); o1 = fmaf(wl[8],  hC.x, o1);
        o1 = fmaf(wl[9],  hC.y, o1);
        o2 = fmaf(wl[10], hC.z, o2); o2 = fmaf(wl[11], hC.w, o2);
        o2 = fmaf(wl[12], hD.x, o2); o2 = fmaf(wl[13], hD.y, o2);
        o2 = fmaf(wl[14], hD.z, o2);
        if (lane < OUTN) out[t2 * OUTN + lane] = o0 + (o1 + o2);
      }
      // prefetch h1[i-3] (for t2 = i-3 computed next iteration)
      if (i - 3 >= 0 && i - 3 < T_SEQ) {
        const float4* p = (const float4*)(&h1buf[(i - 3) & 3][0]);
        nA = p[0]; nB = p[1]; nC = p[2]; nD = p[3];
      }
      wg_barrier();
      hA = nA; hB = nB; hC = nC; hD = nD;
    }
  }
}

// ---------- launch ----------
extern "C" void kernel_launch(void* const* d_in, const int* in_sizes, int n_in,
                              void* d_out, int out_size, void* d_ws, size_t ws_size,
                              hipStream_t stream) {
  const float* x     = (const float*)d_in[0];
  const float* w_ih0 = (const float*)d_in[1];
  const float* w_hh0 = (const float*)d_in[2];
  const float* b_ih0 = (const float*)d_in[3];
  const float* b_hh0 = (const float*)d_in[4];
  const float* w_ih1 = (const float*)d_in[5];
  const float* w_hh1 = (const float*)d_in[6];
  const float* b_ih1 = (const float*)d_in[7];
  const float* b_hh1 = (const float*)d_in[8];
  const float* w_lin = (const float*)d_in[9];
  const float* b_lin = (const float*)d_in[10];
  float* out = (float*)d_out;
  float* xw0 = (float*)d_ws;  // 512*60*4 = 122880 B

  precompute_xw0<<<dim3((T_SEQ * G4 + 255) / 256), dim3(256), 0, stream>>>(
      x, w_ih0, b_ih0, b_hh0, xw0);
  lstm_pipe<<<dim3(1), dim3(192), 0, stream>>>(
      xw0, w_hh0, w_ih1, w_hh1, b_ih1, b_hh1, w_lin, b_lin, out);
}